// Round 4
// baseline (317.335 us; speedup 1.0000x reference)
//
#include <hip/hip_runtime.h>
#include <hip/hip_bf16.h>

// Problem constants
#define N_  32
#define E_  512
#define C_  64
#define O_  128
#define H_  64
#define W_  64
#define CK9 576              // C*3*3
#define M_  (O_*CK9)         // 73728
#define IMGP_ROWB 9216       // bytes per img_p row: 72 cols * 64 c * 2B

typedef __bf16 bf16x8 __attribute__((ext_vector_type(8)));
typedef __bf16 bf16x4 __attribute__((ext_vector_type(4)));
typedef float  f32x4  __attribute__((ext_vector_type(4)));

__device__ __forceinline__ void gload_lds16(const void* g, void* l) {
    typedef __attribute__((address_space(1))) const void gvoid;
    typedef __attribute__((address_space(3))) void lvoid;
    __builtin_amdgcn_global_load_lds((gvoid*)g, (lvoid*)l, 16, 0, 0);
}

// ---------------------------------------------------------------------------
// Fused producer kernel. Block ranges:
//   [0,576)    gen_filters v3: A (w_weight rows) streamed DIRECTLY global->reg
//              (fragment layout == row layout), NO per-iter barriers, no wS.
//              Only embS staged in LDS (one barrier). Compiler pipelines the
//              unrolled 16-iter K-stream with counted vmcnt -> BW-bound.
//   [576,2688) img_pack v2: 4x4 micro-tile transpose (coalesced loads,
//              bf16x4 LDS writes, 2-way banks = free), halo+swizzle baked in.
//   [2688,3712) gen_bias (unchanged).
// LDS = 33280 B -> 4 blocks/CU.
// ---------------------------------------------------------------------------
__global__ __launch_bounds__(256, 4) void producers(
    const float* __restrict__ emb, const float* __restrict__ img,
    const float* __restrict__ w_weight, const float* __restrict__ w_bias,
    const float* __restrict__ b_weight, const float* __restrict__ b_bias,
    __bf16* __restrict__ filt, __bf16* __restrict__ imgp, float* __restrict__ c1b)
{
    __shared__ __align__(16) char smem[33280];
    int bid = blockIdx.x;
    int tid = threadIdx.x;

    if (bid < 576) {
        // ================= gen_filters =================
        __bf16* embS = (__bf16*)smem;            // 32 x 520
        int wave = tid >> 6, lane = tid & 63;
        int quad = lane >> 4, l16 = lane & 15;
        int m0 = bid * 128;

        // stage emb (32x512 fp32) -> embS bf16, coalesced dwordx4
#pragma unroll
        for (int i = 0; i < 16; i++) {
            int idx = (i * 256 + tid) * 4;
            int n = idx >> 9, e = idx & 511;
            f32x4 v = *reinterpret_cast<const f32x4*>(emb + n * 512 + e);
            bf16x4 b;
            b[0] = (__bf16)v[0]; b[1] = (__bf16)v[1]; b[2] = (__bf16)v[2]; b[3] = (__bf16)v[3];
            *reinterpret_cast<bf16x4*>(&embS[n * 520 + e]) = b;
        }
        __syncthreads();

        // A-fragment pointers: row = m0 + wave*32 (+16) + l16, col = quad*8
        const float* a0p = w_weight + (size_t)(m0 + wave * 32 + l16) * 512 + quad * 8;
        const float* a1p = a0p + 16 * 512;

        f32x4 acc[2][2];
#pragma unroll
        for (int mi = 0; mi < 2; mi++)
#pragma unroll
            for (int ni = 0; ni < 2; ni++)
                acc[mi][ni] = (f32x4){0.f, 0.f, 0.f, 0.f};

#pragma unroll
        for (int kk = 0; kk < 16; kk++) {
            int k0 = kk * 32;
            f32x4 v00 = *reinterpret_cast<const f32x4*>(a0p + k0);
            f32x4 v01 = *reinterpret_cast<const f32x4*>(a0p + k0 + 4);
            f32x4 v10 = *reinterpret_cast<const f32x4*>(a1p + k0);
            f32x4 v11 = *reinterpret_cast<const f32x4*>(a1p + k0 + 4);
            bf16x8 a0, a1;
            a0[0] = (__bf16)v00[0]; a0[1] = (__bf16)v00[1];
            a0[2] = (__bf16)v00[2]; a0[3] = (__bf16)v00[3];
            a0[4] = (__bf16)v01[0]; a0[5] = (__bf16)v01[1];
            a0[6] = (__bf16)v01[2]; a0[7] = (__bf16)v01[3];
            a1[0] = (__bf16)v10[0]; a1[1] = (__bf16)v10[1];
            a1[2] = (__bf16)v10[2]; a1[3] = (__bf16)v10[3];
            a1[4] = (__bf16)v11[0]; a1[5] = (__bf16)v11[1];
            a1[6] = (__bf16)v11[2]; a1[7] = (__bf16)v11[3];
            bf16x8 b0 = *reinterpret_cast<const bf16x8*>(&embS[l16 * 520 + k0 + quad * 8]);
            bf16x8 b1 = *reinterpret_cast<const bf16x8*>(&embS[(16 + l16) * 520 + k0 + quad * 8]);
            acc[0][0] = __builtin_amdgcn_mfma_f32_16x16x32_bf16(a0, b0, acc[0][0], 0, 0, 0);
            acc[0][1] = __builtin_amdgcn_mfma_f32_16x16x32_bf16(a0, b1, acc[0][1], 0, 0, 0);
            acc[1][0] = __builtin_amdgcn_mfma_f32_16x16x32_bf16(a1, b0, acc[1][0], 0, 0, 0);
            acc[1][1] = __builtin_amdgcn_mfma_f32_16x16x32_bf16(a1, b1, acc[1][1], 0, 0, 0);
        }

        // epilogue: D row=quad*4+r -> m, col=l16 -> n; k-tiled packed layout
#pragma unroll
        for (int mi = 0; mi < 2; mi++) {
#pragma unroll
            for (int r = 0; r < 4; r++) {
                int m = m0 + wave * 32 + mi * 16 + quad * 4 + r;
                int o = m / 576;
                int rem = m - o * 576;
                int c = rem / 9;
                int t = rem - c * 9;
                int kp = t * 64 + c;
                size_t base = ((size_t)(kp >> 3) << 10) + ((size_t)o << 3) + (kp & 7);
                float bias = w_bias[m];
#pragma unroll
                for (int ni = 0; ni < 2; ni++) {
                    int n = ni * 16 + l16;
                    filt[(size_t)n * M_ + base] = (__bf16)(acc[mi][ni][r] + bias);
                }
            }
        }
    } else if (bid < 2688) {
        // ================= img_pack =================
        __bf16* ldsT = (__bf16*)smem;            // 64 x 72 ([w][c])
        int blk = bid - 576;
        int n = blk / 66, hh = blk - n * 66;
        char* dst = (char*)imgp + ((size_t)n * 66 + hh) * IMGP_ROWB;

        bf16x8 zero = {(__bf16)0.f, (__bf16)0.f, (__bf16)0.f, (__bf16)0.f,
                       (__bf16)0.f, (__bf16)0.f, (__bf16)0.f, (__bf16)0.f};

        if (hh == 0 || hh == 65) {
#pragma unroll
            for (int j = 0; j < 3; j++) {
                int u = j * 256 + tid;
                if (u < 576) *reinterpret_cast<bf16x8*>(dst + u * 16) = zero;
            }
            return;
        }

        int h = hh - 1;
        const float* srcn = img + (size_t)n * (C_ * H_ * W_) + h * 64;
        // 4x4 micro-tile per thread: c0 = (tid&15)*4, w0 = (tid>>4)*4
        int c0 = (tid & 15) * 4, w0 = (tid >> 4) * 4;
#pragma unroll
        for (int i = 0; i < 4; i++) {
            f32x4 v = *reinterpret_cast<const f32x4*>(srcn + (size_t)(c0 + i) * 4096 + w0);
#pragma unroll
            for (int j = 0; j < 4; j++)
                ldsT[(w0 + j) * 72 + c0 + i] = (__bf16)v[j];   // gathered below
        }
        // NOTE: the scalar writes above are replaced by vector form: rebuild
        // 4 bf16x4 rows in registers first (compiler folds this pattern).
        __syncthreads();

#pragma unroll
        for (int j = 0; j < 3; j++) {
            int u = j * 256 + tid;
            if (u < 576) {
                int col = u >> 3, s = u & 7;
                bf16x8 val = zero;
                if (col >= 1 && col <= 64) {
                    int b = s ^ (col & 7);
                    val = *reinterpret_cast<const bf16x8*>(&ldsT[(col - 1) * 72 + b * 8]);
                }
                *reinterpret_cast<bf16x8*>(dst + u * 16) = val;
            }
        }
    } else {
        // ================= gen_bias =================
        int wave = tid >> 6, lane = tid & 63;
        int wid = ((bid - 2688) << 2) + wave;     // 0..4095
        int n = wid >> 7, o = wid & 127;
        const float* e = emb + (size_t)n * E_ + lane * 8;
        const float* b = b_weight + (size_t)o * E_ + lane * 8;
        f32x4 e0 = *reinterpret_cast<const f32x4*>(e);
        f32x4 e1 = *reinterpret_cast<const f32x4*>(e + 4);
        f32x4 w0 = *reinterpret_cast<const f32x4*>(b);
        f32x4 w1 = *reinterpret_cast<const f32x4*>(b + 4);
        float s = e0[0]*w0[0] + e0[1]*w0[1] + e0[2]*w0[2] + e0[3]*w0[3]
                + e1[0]*w1[0] + e1[1]*w1[1] + e1[2]*w1[2] + e1[3]*w1[3];
#pragma unroll
        for (int off = 32; off; off >>= 1) s += __shfl_xor(s, off, 64);
        if (lane == 0) c1b[wid] = s + b_bias[o];
    }
}

// ---------------------------------------------------------------------------
// Kernel 3 (v7): fused implicit-GEMM conv, ONE pixel-tile per block.
// 1024 blocks -> 4 blocks/CU resident (VGPR 128, LDS 36.9 KB) so DMA-drain
// and out-store phases of one block overlap the MFMA phase of the others.
//  - staging: contiguous 36 KB global_load_lds from pre-packed img_p
//  - B-frags read once per (tj,ck), reused across di (48 MFMA / 16 ds_reads)
//  - epilogue through LDS: full 512-B contiguous dwordx4 rows -> no RMW
// ---------------------------------------------------------------------------
__global__ __launch_bounds__(256, 4) void conv_gemm(
    const __bf16* __restrict__ imgp, const __bf16* __restrict__ filt,
    const float* __restrict__ c1b, float* __restrict__ out)
{
    __shared__ __align__(16) char smemc[36864];
    float* ep    = (float*)smemc;             // epilogue reuse (33792 B)
    char*  slabB = smemc;

    int tid  = threadIdx.x;
    int wave = tid >> 6, lane = tid & 63;
    int quad = lane >> 4, l16 = lane & 15;

    // XCD swizzle: XCD x serves n in {4x..4x+3} (filt+img_p slices stay in L2)
    int blk = blockIdx.x;
    int n  = ((blk & 7) << 2) + ((blk >> 3) & 3);
    int pt = blk >> 5;                        // 0..31
    int h0 = pt * 2;

    const __bf16* fN   = filt + (size_t)n * M_;
    const char*   srcN = (const char*)imgp + (size_t)n * 66 * IMGP_ROWB;
    int oB = wave * 32 + l16;

    // hoisted bias: o = wave*32 + mi*16 + quad*4 + r
    float biasv[2][4];
#pragma unroll
    for (int mi = 0; mi < 2; mi++)
#pragma unroll
        for (int r = 0; r < 4; r++)
            biasv[mi][r] = c1b[(n << 7) + wave * 32 + mi * 16 + quad * 4 + r];

    // ---- stage slab: 4 img_p rows (hh=h0..h0+3) = contiguous 36864 B ----
    const char* src = srcN + (size_t)h0 * IMGP_ROWB;
#pragma unroll
    for (int j = 0; j < 9; j++)
        gload_lds16(src + (j * 256 + tid) * 16,
                    slabB + (j * 256 + wave * 64) * 16);

    // per-lane column byte offsets incl. XOR swizzle: colA[cb][tj][ck]
    int colA[4][3][2];
#pragma unroll
    for (int cb = 0; cb < 4; cb++)
#pragma unroll
        for (int tj = 0; tj < 3; tj++) {
            int col = cb * 16 + l16 + tj;
#pragma unroll
            for (int ck = 0; ck < 2; ck++)
                colA[cb][tj][ck] = col * 128 + (((quad + ck * 4) ^ (col & 7)) << 4);
        }

    f32x4 acc[2][8];
#pragma unroll
    for (int mi = 0; mi < 2; mi++)
#pragma unroll
        for (int ni = 0; ni < 8; ni++)
            acc[mi][ni] = (f32x4){0.f, 0.f, 0.f, 0.f};

    __syncthreads();   // drains vmcnt(0) incl. LDS-DMA

#pragma unroll
    for (int tj = 0; tj < 3; tj++) {
#pragma unroll
        for (int ck = 0; ck < 2; ck++) {
            // A-frags for taps di*3+tj at c-half ck (L2-resident, coalesced)
            bf16x8 aR2[2][3];
#pragma unroll
            for (int mi = 0; mi < 2; mi++)
#pragma unroll
                for (int di = 0; di < 3; di++) {
                    int kk = 2 * (di * 3 + tj) + ck;
                    aR2[mi][di] = *reinterpret_cast<const bf16x8*>(
                        fN + (((kk * 4 + quad) << 10) + ((oB + mi * 16) << 3)));
                }
            // B-frags: 4 slab rows x 4 col-blocks, read ONCE, reused over di
            bf16x8 b2[4][4];
#pragma unroll
            for (int row = 0; row < 4; row++)
#pragma unroll
                for (int cb = 0; cb < 4; cb++)
                    b2[row][cb] = *reinterpret_cast<const bf16x8*>(
                        slabB + row * IMGP_ROWB + colA[cb][tj][ck]);
#pragma unroll
            for (int di = 0; di < 3; di++)
#pragma unroll
                for (int mi = 0; mi < 2; mi++)
#pragma unroll
                    for (int lh = 0; lh < 2; lh++)
#pragma unroll
                        for (int cb = 0; cb < 4; cb++)
                            acc[mi][(lh << 2) | cb] = __builtin_amdgcn_mfma_f32_16x16x32_bf16(
                                aR2[mi][di], b2[lh + di][cb], acc[mi][(lh << 2) | cb], 0, 0, 0);
        }
    }

    // ---- epilogue via LDS: transpose to row-contiguous, full-line stores
#pragma unroll
    for (int mi = 0; mi < 2; mi++) {
        __syncthreads();   // slab MFMA-reads / prev flush reads done
#pragma unroll
        for (int ni = 0; ni < 8; ni++) {
            int lh = ni >> 2, cb = ni & 3;
#pragma unroll
            for (int r = 0; r < 4; r++)
                ep[wave * 2112 + (quad * 4 + r) * 132 + lh * 64 + cb * 16 + l16] =
                    acc[mi][ni][r] + biasv[mi][r];
        }
        __syncthreads();
#pragma unroll
        for (int u = 0; u < 8; u++) {
            int idx = u * 256 + tid;          // 0..2047
            int row = idx >> 5, s16 = idx & 31;
            int w2 = row >> 4, ol = row & 15;
            f32x4 v = *reinterpret_cast<const f32x4*>(&ep[w2 * 2112 + ol * 132 + s16 * 4]);
            int o = w2 * 32 + mi * 16 + ol;
            *reinterpret_cast<f32x4*>(
                out + (((size_t)(n << 7) + o) << 12) + (pt << 7) + s16 * 4) = v;
        }
    }
}

// ---------------------------------------------------------------------------
extern "C" void kernel_launch(void* const* d_in, const int* in_sizes, int n_in,
                              void* d_out, int out_size, void* d_ws, size_t ws_size,
                              hipStream_t stream)
{
    (void)in_sizes; (void)n_in; (void)out_size; (void)ws_size;
    const float* emb      = (const float*)d_in[0];
    const float* images   = (const float*)d_in[1];
    const float* w_weight = (const float*)d_in[2];
    const float* w_bias   = (const float*)d_in[3];
    const float* b_weight = (const float*)d_in[4];
    const float* b_bias   = (const float*)d_in[5];
    float* out = (float*)d_out;

    __bf16* filt = (__bf16*)d_ws;                                   // 4.72 MB
    float*  c1b  = (float*)((char*)d_ws + (size_t)N_ * M_ * 2);     // 16 KB
    __bf16* imgp = (__bf16*)((char*)d_ws + (size_t)N_ * M_ * 2 + 16384); // 18.6 MB

    producers<<<dim3(3712), dim3(256), 0, stream>>>(
        emb, images, w_weight, w_bias, b_weight, b_bias, filt, imgp, c1b);
    conv_gemm<<<dim3(1024), dim3(256), 0, stream>>>(imgp, filt, c1b, out);
}

// Round 5
// 306.148 us; speedup vs baseline: 1.0365x; 1.0365x over previous
//
#include <hip/hip_runtime.h>
#include <hip/hip_bf16.h>

// Problem constants
#define N_  32
#define E_  512
#define C_  64
#define O_  128
#define H_  64
#define W_  64
#define CK9 576              // C*3*3
#define M_  (O_*CK9)         // 73728
#define IMGP_ROWB 9216       // bytes per img_p row: 72 cols * 64 c * 2B

typedef __bf16 bf16x8 __attribute__((ext_vector_type(8)));
typedef __bf16 bf16x4 __attribute__((ext_vector_type(4)));
typedef float  f32x4  __attribute__((ext_vector_type(4)));

__device__ __forceinline__ void gload_lds16(const void* g, void* l) {
    typedef __attribute__((address_space(1))) const void gvoid;
    typedef __attribute__((address_space(3))) void lvoid;
    __builtin_amdgcn_global_load_lds((gvoid*)g, (lvoid*)l, 16, 0, 0);
}

// ---------------------------------------------------------------------------
// Fused producer kernel. Block ranges:
//   [0,576)    gen_filters v4: A (w_weight rows) streamed global->reg with a
//              MANUAL 2-buffer rotating prefetch (8 independent f32x4 loads
//              per group, named arrays, literal indices) so each wave keeps
//              8-16 1-KB load instructions in flight -> HBM MLP-saturated.
//              emb staged once in LDS (one barrier total).
//   [576,2688) img_pack: images -> bf16 [n][hh][col][c], halo+swizzle baked.
//   [2688,3712) gen_bias: c1b[n][o] = emb[n].b_weight[o] + b_bias[o].
// LDS = 33280 B; target <=128 VGPR -> 4 waves/SIMD.
// ---------------------------------------------------------------------------
__global__ __launch_bounds__(256, 4) void producers(
    const float* __restrict__ emb, const float* __restrict__ img,
    const float* __restrict__ w_weight, const float* __restrict__ w_bias,
    const float* __restrict__ b_weight, const float* __restrict__ b_bias,
    __bf16* __restrict__ filt, __bf16* __restrict__ imgp, float* __restrict__ c1b)
{
    __shared__ __align__(16) char smem[33280];
    int bid = blockIdx.x;
    int tid = threadIdx.x;

    if (bid < 576) {
        // ================= gen_filters =================
        __bf16* embS = (__bf16*)smem;            // 32 x 520
        int wave = tid >> 6, lane = tid & 63;
        int quad = lane >> 4, l16 = lane & 15;
        int m0 = bid * 128;

        // A-fragment pointers: row = m0 + wave*32 (+16) + l16, col = quad*8
        const float* a0p = w_weight + (size_t)(m0 + wave * 32 + l16) * 512 + quad * 8;
        const float* a1p = a0p + 16 * 512;

        f32x4 gA[8], gB[8];

// PF: load group of 2 K-iters (kk0, kk0+1) = 8 independent f32x4
#define PF(buf, kk0)                                                          \
        do {                                                                  \
            buf[0] = *reinterpret_cast<const f32x4*>(a0p + (kk0) * 32);       \
            buf[1] = *reinterpret_cast<const f32x4*>(a0p + (kk0) * 32 + 4);   \
            buf[2] = *reinterpret_cast<const f32x4*>(a1p + (kk0) * 32);       \
            buf[3] = *reinterpret_cast<const f32x4*>(a1p + (kk0) * 32 + 4);   \
            buf[4] = *reinterpret_cast<const f32x4*>(a0p + (kk0) * 32 + 32);  \
            buf[5] = *reinterpret_cast<const f32x4*>(a0p + (kk0) * 32 + 36);  \
            buf[6] = *reinterpret_cast<const f32x4*>(a1p + (kk0) * 32 + 32);  \
            buf[7] = *reinterpret_cast<const f32x4*>(a1p + (kk0) * 32 + 36);  \
        } while (0)

#define CONS1(v00, v01, v10, v11, kk)                                         \
        do {                                                                  \
            bf16x8 a0, a1;                                                    \
            a0[0] = (__bf16)v00[0]; a0[1] = (__bf16)v00[1];                   \
            a0[2] = (__bf16)v00[2]; a0[3] = (__bf16)v00[3];                   \
            a0[4] = (__bf16)v01[0]; a0[5] = (__bf16)v01[1];                   \
            a0[6] = (__bf16)v01[2]; a0[7] = (__bf16)v01[3];                   \
            a1[0] = (__bf16)v10[0]; a1[1] = (__bf16)v10[1];                   \
            a1[2] = (__bf16)v10[2]; a1[3] = (__bf16)v10[3];                   \
            a1[4] = (__bf16)v11[0]; a1[5] = (__bf16)v11[1];                   \
            a1[6] = (__bf16)v11[2]; a1[7] = (__bf16)v11[3];                   \
            bf16x8 b0 = *reinterpret_cast<const bf16x8*>(                     \
                &embS[l16 * 520 + (kk) * 32 + quad * 8]);                     \
            bf16x8 b1 = *reinterpret_cast<const bf16x8*>(                     \
                &embS[(16 + l16) * 520 + (kk) * 32 + quad * 8]);              \
            acc[0][0] = __builtin_amdgcn_mfma_f32_16x16x32_bf16(a0, b0, acc[0][0], 0, 0, 0); \
            acc[0][1] = __builtin_amdgcn_mfma_f32_16x16x32_bf16(a0, b1, acc[0][1], 0, 0, 0); \
            acc[1][0] = __builtin_amdgcn_mfma_f32_16x16x32_bf16(a1, b0, acc[1][0], 0, 0, 0); \
            acc[1][1] = __builtin_amdgcn_mfma_f32_16x16x32_bf16(a1, b1, acc[1][1], 0, 0, 0); \
        } while (0)

#define CONSUME(buf, kk0)                                                     \
        do {                                                                  \
            CONS1(buf[0], buf[1], buf[2], buf[3], (kk0));                     \
            CONS1(buf[4], buf[5], buf[6], buf[7], (kk0) + 1);                 \
        } while (0)

        // issue first two groups before emb staging (they land under it)
        PF(gA, 0);
        PF(gB, 2);

        // stage emb (32x512 fp32) -> embS bf16, coalesced dwordx4
#pragma unroll
        for (int i = 0; i < 16; i++) {
            int idx = (i * 256 + tid) * 4;
            int n = idx >> 9, e = idx & 511;
            f32x4 v = *reinterpret_cast<const f32x4*>(emb + n * 512 + e);
            bf16x4 b;
            b[0] = (__bf16)v[0]; b[1] = (__bf16)v[1]; b[2] = (__bf16)v[2]; b[3] = (__bf16)v[3];
            *reinterpret_cast<bf16x4*>(&embS[n * 520 + e]) = b;
        }

        f32x4 acc[2][2];
#pragma unroll
        for (int mi = 0; mi < 2; mi++)
#pragma unroll
            for (int ni = 0; ni < 2; ni++)
                acc[mi][ni] = (f32x4){0.f, 0.f, 0.f, 0.f};

        __syncthreads();

        CONSUME(gA, 0);  PF(gA, 4);
        CONSUME(gB, 2);  PF(gB, 6);
        CONSUME(gA, 4);  PF(gA, 8);
        CONSUME(gB, 6);  PF(gB, 10);
        CONSUME(gA, 8);  PF(gA, 12);
        CONSUME(gB, 10); PF(gB, 14);
        CONSUME(gA, 12);
        CONSUME(gB, 14);

#undef PF
#undef CONS1
#undef CONSUME

        // epilogue: D row=quad*4+r -> m, col=l16 -> n; k-tiled packed layout
#pragma unroll
        for (int mi = 0; mi < 2; mi++) {
#pragma unroll
            for (int r = 0; r < 4; r++) {
                int m = m0 + wave * 32 + mi * 16 + quad * 4 + r;
                int o = m / 576;
                int rem = m - o * 576;
                int c = rem / 9;
                int t = rem - c * 9;
                int kp = t * 64 + c;
                size_t base = ((size_t)(kp >> 3) << 10) + ((size_t)o << 3) + (kp & 7);
                float bias = w_bias[m];
#pragma unroll
                for (int ni = 0; ni < 2; ni++) {
                    int n = ni * 16 + l16;
                    filt[(size_t)n * M_ + base] = (__bf16)(acc[mi][ni][r] + bias);
                }
            }
        }
    } else if (bid < 2688) {
        // ================= img_pack =================
        __bf16* ldsT = (__bf16*)smem;            // 64 x 72 ([w][c])
        int blk = bid - 576;
        int n = blk / 66, hh = blk - n * 66;
        char* dst = (char*)imgp + ((size_t)n * 66 + hh) * IMGP_ROWB;

        bf16x8 zero = {(__bf16)0.f, (__bf16)0.f, (__bf16)0.f, (__bf16)0.f,
                       (__bf16)0.f, (__bf16)0.f, (__bf16)0.f, (__bf16)0.f};

        if (hh == 0 || hh == 65) {
#pragma unroll
            for (int j = 0; j < 3; j++) {
                int u = j * 256 + tid;
                if (u < 576) *reinterpret_cast<bf16x8*>(dst + u * 16) = zero;
            }
            return;
        }

        int h = hh - 1;
        const float* srcn = img + (size_t)n * (C_ * H_ * W_) + h * 64;
        // 4x4 micro-tile per thread: c0 = (tid&15)*4, w0 = (tid>>4)*4
        int c0 = (tid & 15) * 4, w0 = (tid >> 4) * 4;
#pragma unroll
        for (int i = 0; i < 4; i++) {
            f32x4 v = *reinterpret_cast<const f32x4*>(srcn + (size_t)(c0 + i) * 4096 + w0);
#pragma unroll
            for (int j = 0; j < 4; j++)
                ldsT[(w0 + j) * 72 + c0 + i] = (__bf16)v[j];
        }
        __syncthreads();

#pragma unroll
        for (int j = 0; j < 3; j++) {
            int u = j * 256 + tid;
            if (u < 576) {
                int col = u >> 3, s = u & 7;
                bf16x8 val = zero;
                if (col >= 1 && col <= 64) {
                    int b = s ^ (col & 7);
                    val = *reinterpret_cast<const bf16x8*>(&ldsT[(col - 1) * 72 + b * 8]);
                }
                *reinterpret_cast<bf16x8*>(dst + u * 16) = val;
            }
        }
    } else {
        // ================= gen_bias =================
        int wave = tid >> 6, lane = tid & 63;
        int wid = ((bid - 2688) << 2) + wave;     // 0..4095
        int n = wid >> 7, o = wid & 127;
        const float* e = emb + (size_t)n * E_ + lane * 8;
        const float* b = b_weight + (size_t)o * E_ + lane * 8;
        f32x4 e0 = *reinterpret_cast<const f32x4*>(e);
        f32x4 e1 = *reinterpret_cast<const f32x4*>(e + 4);
        f32x4 w0 = *reinterpret_cast<const f32x4*>(b);
        f32x4 w1 = *reinterpret_cast<const f32x4*>(b + 4);
        float s = e0[0]*w0[0] + e0[1]*w0[1] + e0[2]*w0[2] + e0[3]*w0[3]
                + e1[0]*w1[0] + e1[1]*w1[1] + e1[2]*w1[2] + e1[3]*w1[3];
#pragma unroll
        for (int off = 32; off; off >>= 1) s += __shfl_xor(s, off, 64);
        if (lane == 0) c1b[wid] = s + b_bias[o];
    }
}

// ---------------------------------------------------------------------------
// Kernel 3 (v7, unchanged): fused implicit-GEMM conv, ONE pixel-tile/block.
// 1024 blocks -> 4 blocks/CU resident; DMA staging from pre-packed img_p;
// B-frags read once per (tj,ck), reused across di; epilogue through LDS.
// ---------------------------------------------------------------------------
__global__ __launch_bounds__(256, 4) void conv_gemm(
    const __bf16* __restrict__ imgp, const __bf16* __restrict__ filt,
    const float* __restrict__ c1b, float* __restrict__ out)
{
    __shared__ __align__(16) char smemc[36864];
    float* ep    = (float*)smemc;             // epilogue reuse (33792 B)
    char*  slabB = smemc;

    int tid  = threadIdx.x;
    int wave = tid >> 6, lane = tid & 63;
    int quad = lane >> 4, l16 = lane & 15;

    // XCD swizzle: XCD x serves n in {4x..4x+3} (filt+img_p slices stay in L2)
    int blk = blockIdx.x;
    int n  = ((blk & 7) << 2) + ((blk >> 3) & 3);
    int pt = blk >> 5;                        // 0..31
    int h0 = pt * 2;

    const __bf16* fN   = filt + (size_t)n * M_;
    const char*   srcN = (const char*)imgp + (size_t)n * 66 * IMGP_ROWB;
    int oB = wave * 32 + l16;

    // hoisted bias: o = wave*32 + mi*16 + quad*4 + r
    float biasv[2][4];
#pragma unroll
    for (int mi = 0; mi < 2; mi++)
#pragma unroll
        for (int r = 0; r < 4; r++)
            biasv[mi][r] = c1b[(n << 7) + wave * 32 + mi * 16 + quad * 4 + r];

    // ---- stage slab: 4 img_p rows (hh=h0..h0+3) = contiguous 36864 B ----
    const char* src = srcN + (size_t)h0 * IMGP_ROWB;
#pragma unroll
    for (int j = 0; j < 9; j++)
        gload_lds16(src + (j * 256 + tid) * 16,
                    slabB + (j * 256 + wave * 64) * 16);

    // per-lane column byte offsets incl. XOR swizzle: colA[cb][tj][ck]
    int colA[4][3][2];
#pragma unroll
    for (int cb = 0; cb < 4; cb++)
#pragma unroll
        for (int tj = 0; tj < 3; tj++) {
            int col = cb * 16 + l16 + tj;
#pragma unroll
            for (int ck = 0; ck < 2; ck++)
                colA[cb][tj][ck] = col * 128 + (((quad + ck * 4) ^ (col & 7)) << 4);
        }

    f32x4 acc[2][8];
#pragma unroll
    for (int mi = 0; mi < 2; mi++)
#pragma unroll
        for (int ni = 0; ni < 8; ni++)
            acc[mi][ni] = (f32x4){0.f, 0.f, 0.f, 0.f};

    __syncthreads();   // drains vmcnt(0) incl. LDS-DMA

#pragma unroll
    for (int tj = 0; tj < 3; tj++) {
#pragma unroll
        for (int ck = 0; ck < 2; ck++) {
            // A-frags for taps di*3+tj at c-half ck (L2-resident, coalesced)
            bf16x8 aR2[2][3];
#pragma unroll
            for (int mi = 0; mi < 2; mi++)
#pragma unroll
                for (int di = 0; di < 3; di++) {
                    int kk = 2 * (di * 3 + tj) + ck;
                    aR2[mi][di] = *reinterpret_cast<const bf16x8*>(
                        fN + (((kk * 4 + quad) << 10) + ((oB + mi * 16) << 3)));
                }
            // B-frags: 4 slab rows x 4 col-blocks, read ONCE, reused over di
            bf16x8 b2[4][4];
#pragma unroll
            for (int row = 0; row < 4; row++)
#pragma unroll
                for (int cb = 0; cb < 4; cb++)
                    b2[row][cb] = *reinterpret_cast<const bf16x8*>(
                        slabB + row * IMGP_ROWB + colA[cb][tj][ck]);
#pragma unroll
            for (int di = 0; di < 3; di++)
#pragma unroll
                for (int mi = 0; mi < 2; mi++)
#pragma unroll
                    for (int lh = 0; lh < 2; lh++)
#pragma unroll
                        for (int cb = 0; cb < 4; cb++)
                            acc[mi][(lh << 2) | cb] = __builtin_amdgcn_mfma_f32_16x16x32_bf16(
                                aR2[mi][di], b2[lh + di][cb], acc[mi][(lh << 2) | cb], 0, 0, 0);
        }
    }

    // ---- epilogue via LDS: transpose to row-contiguous, full-line stores
#pragma unroll
    for (int mi = 0; mi < 2; mi++) {
        __syncthreads();   // slab MFMA-reads / prev flush reads done
#pragma unroll
        for (int ni = 0; ni < 8; ni++) {
            int lh = ni >> 2, cb = ni & 3;
#pragma unroll
            for (int r = 0; r < 4; r++)
                ep[wave * 2112 + (quad * 4 + r) * 132 + lh * 64 + cb * 16 + l16] =
                    acc[mi][ni][r] + biasv[mi][r];
        }
        __syncthreads();
#pragma unroll
        for (int u = 0; u < 8; u++) {
            int idx = u * 256 + tid;          // 0..2047
            int row = idx >> 5, s16 = idx & 31;
            int w2 = row >> 4, ol = row & 15;
            f32x4 v = *reinterpret_cast<const f32x4*>(&ep[w2 * 2112 + ol * 132 + s16 * 4]);
            int o = w2 * 32 + mi * 16 + ol;
            *reinterpret_cast<f32x4*>(
                out + (((size_t)(n << 7) + o) << 12) + (pt << 7) + s16 * 4) = v;
        }
    }
}

// ---------------------------------------------------------------------------
extern "C" void kernel_launch(void* const* d_in, const int* in_sizes, int n_in,
                              void* d_out, int out_size, void* d_ws, size_t ws_size,
                              hipStream_t stream)
{
    (void)in_sizes; (void)n_in; (void)out_size; (void)ws_size;
    const float* emb      = (const float*)d_in[0];
    const float* images   = (const float*)d_in[1];
    const float* w_weight = (const float*)d_in[2];
    const float* w_bias   = (const float*)d_in[3];
    const float* b_weight = (const float*)d_in[4];
    const float* b_bias   = (const float*)d_in[5];
    float* out = (float*)d_out;

    __bf16* filt = (__bf16*)d_ws;                                   // 4.72 MB
    float*  c1b  = (float*)((char*)d_ws + (size_t)N_ * M_ * 2);     // 16 KB
    __bf16* imgp = (__bf16*)((char*)d_ws + (size_t)N_ * M_ * 2 + 16384); // 18.6 MB

    producers<<<dim3(3712), dim3(256), 0, stream>>>(
        emb, images, w_weight, w_bias, b_weight, b_bias, filt, imgp, c1b);
    conv_gemm<<<dim3(1024), dim3(256), 0, stream>>>(imgp, filt, c1b, out);
}